// Round 8
// baseline (607.121 us; speedup 1.0000x reference)
//
#include <hip/hip_runtime.h>

typedef unsigned short u16;
typedef unsigned int   u32;
typedef __bf16  bf16x8 __attribute__((ext_vector_type(8)));
typedef u16     u16x8  __attribute__((ext_vector_type(8)));
typedef float   f32x4  __attribute__((ext_vector_type(4)));

#define S_LEN   4096
#define DMODEL  512
#define NBATCH  4
#define NTILE   32          // S/128
#define NPAIR   528         // NTILE*(NTILE+1)/2
#define SCALE   0.044194173824159216f   // 1/sqrt(512)

__device__ __forceinline__ u16 f2bf(float x){
  u32 u = __float_as_uint(x);
  return (u16)((u + 0x7fffu + ((u >> 16) & 1u)) >> 16);   // RNE
}
__device__ __forceinline__ float bf2f(u16 u){ return __uint_as_float(((u32)u) << 16); }

// 16 MFMA of one 64x64x32 step
#define MFMA16(aa, bb) { _Pragma("unroll") \
  for (int m_ = 0; m_ < 4; m_++){ _Pragma("unroll") \
    for (int n_ = 0; n_ < 4; n_++) \
      acc[m_][n_] = __builtin_amdgcn_mfma_f32_16x16x32_bf16(aa[m_], bb[n_], acc[m_][n_], 0, 0, 0); } }

// fragment loads for K-contiguous (NT) operands, ld = DMODEL
#define LOADQK(s_, aa, bb) { _Pragma("unroll") \
  for (int m_ = 0; m_ < 4; m_++){ \
    aa[m_] = *(const bf16x8*)(Ap + (size_t)m_*16*DMODEL + (s_)*32); \
    bb[m_] = *(const bf16x8*)(Bp + (size_t)m_*16*DMODEL + (s_)*32); } }

// ---------------- casts f32 -> bf16 (3 tensors per launch) --------
__global__ __launch_bounds__(256) void cast3_kernel(const float* __restrict__ a,
                                                    const float* __restrict__ b,
                                                    const float* __restrict__ c,
                                                    u16* oa, u16* ob, u16* oc, int n8){
  int z = blockIdx.y;
  const float* in = (z == 0) ? a : (z == 1) ? b : c;
  u16* out = (z == 0) ? oa : (z == 1) ? ob : oc;
  int i = blockIdx.x * 256 + threadIdx.x;
  int stride = gridDim.x * 256;
  for (; i < n8; i += stride){
    const float4* p = (const float4*)in + (size_t)i * 2;
    float4 x = p[0], y = p[1];
    ushort4 o0 = make_ushort4(f2bf(x.x), f2bf(x.y), f2bf(x.z), f2bf(x.w));
    ushort4 o1 = make_ushort4(f2bf(y.x), f2bf(y.y), f2bf(y.z), f2bf(y.w));
    ((ushort4*)out)[(size_t)i*2]   = o0;
    ((ushort4*)out)[(size_t)i*2+1] = o1;
  }
}

__global__ __launch_bounds__(256) void zero_kernel(float* __restrict__ p, int n){
  int i = blockIdx.x * 256 + threadIdx.x;
  if (i < n) p[i] = 0.f;
}

// ---------------- projections: Y = X * W^T + bias -----------------
// single-wave 64x64 tile, all-register NT GEMM (no LDS, no barriers)
__global__ __launch_bounds__(64) void proj_kernel(
    const u16* __restrict__ qx, const u16* __restrict__ kx, const u16* __restrict__ vx,
    const u16* __restrict__ Wq, const u16* __restrict__ Wk, const u16* __restrict__ Wv,
    const float* __restrict__ bq, const float* __restrict__ bk, const float* __restrict__ bv,
    u16* Qb, u16* Kb, u16* Vb)
{
  int z = blockIdx.z;
  const u16* X = (z==0) ? qx : (z==1) ? kx : vx;
  const u16* W = (z==0) ? Wq : (z==1) ? Wk : Wv;
  const float* bias = (z==0) ? bq : (z==1) ? bk : bv;
  u16* Y = (z==0) ? Qb : (z==1) ? Kb : Vb;

  int cn = blockIdx.x, rm = blockIdx.y;
  int l = threadIdx.x, lo = l & 15, hi = l >> 4;

  f32x4 acc[4][4];
  #pragma unroll
  for (int m = 0; m < 4; m++)
    #pragma unroll
    for (int n = 0; n < 4; n++) acc[m][n] = (f32x4){0.f,0.f,0.f,0.f};

  const u16* Ap = X + ((size_t)rm*64 + lo) * DMODEL + hi*8;
  const u16* Bp = W + ((size_t)cn*64 + lo) * DMODEL + hi*8;
  bf16x8 a0[4], b0[4], a1[4], b1[4];
  LOADQK(0, a0, b0);
  #pragma unroll
  for (int t2 = 0; t2 < 16; t2 += 2){
    LOADQK(t2+1, a1, b1);
    MFMA16(a0, b0);
    if (t2 + 2 < 16) LOADQK(t2+2, a0, b0);
    MFMA16(a1, b1);
  }

  #pragma unroll
  for (int n = 0; n < 4; n++){
    int col = cn*64 + n*16 + lo;
    float bs = bias[col];
    #pragma unroll
    for (int m = 0; m < 4; m++){
      int row0 = rm*64 + m*16 + hi*4;
      #pragma unroll
      for (int j = 0; j < 4; j++)
        Y[(size_t)(row0 + j) * DMODEL + col] = f2bf(acc[m][n][j] + bs);
    }
  }
}

// ---------------- V transpose -------------------------------------
__global__ __launch_bounds__(256) void transpose_kernel(const u16* __restrict__ V,
                                                        u16* __restrict__ Vt)
{
  __shared__ u16 tile[64][66];
  int k0 = blockIdx.x * 64, c0 = blockIdx.y * 64, b = blockIdx.z;
  int t = threadIdx.x;
  #pragma unroll
  for (int i = 0; i < 16; i++){
    int idx = i*256 + t; int r = idx >> 6, c = idx & 63;
    tile[r][c] = V[((size_t)b*S_LEN + k0 + r) * DMODEL + c0 + c];
  }
  __syncthreads();
  #pragma unroll
  for (int i = 0; i < 16; i++){
    int idx = i*256 + t; int r = idx >> 6, c = idx & 63;
    Vt[((size_t)b*DMODEL + c0 + r) * S_LEN + k0 + c] = tile[c][r];
  }
}

// ---------------- V per-tile column sums + suffix scan ------------
__global__ __launch_bounds__(256) void vpart_kernel(const u16* __restrict__ V,
                                                    float* __restrict__ part){
  int t = blockIdx.x, b = blockIdx.y, c = threadIdx.x;
  const u16* base = V + ((size_t)b*S_LEN + t*128) * DMODEL;
  float s0 = 0.f, s1 = 0.f;
  for (int k = 0; k < 128; k++){
    s0 += bf2f(base[(size_t)k*DMODEL + c]);
    s1 += bf2f(base[(size_t)k*DMODEL + 256 + c]);
  }
  part[((size_t)b*NTILE + t)*DMODEL + c]       = s0;
  part[((size_t)b*NTILE + t)*DMODEL + 256 + c] = s1;
}

__global__ void suffix_kernel(const float* __restrict__ part, float* __restrict__ sufx){
  int b = blockIdx.x, c = threadIdx.x;
  float s = 0.f;
  for (int t = NTILE - 1; t >= 0; t--){
    sufx[((size_t)b*NTILE + t)*DMODEL + c] = s;
    s += part[((size_t)b*NTILE + t)*DMODEL + c];
  }
}

// ---------------- score: single-wave 64x64 all-register -----------
// P = exp(mask(Q K^T * scale)), tile rowsums atomically added to Z.
__global__ __launch_bounds__(64) void score_kernel(const u16* __restrict__ Q,
                                                   const u16* __restrict__ K,
                                                   u16* __restrict__ P,
                                                   float* __restrict__ Z)
{
  int flat = blockIdx.x;
  int w = (flat & 7) * 1056 + (flat >> 3);       // XCD chunk swizzle (8448 = 8*1056)
  int b = w / 2112, r = w % 2112;
  int tp = (int)((sqrtf(1.f + 2.f*(float)r) - 1.f) * 0.5f);
  while (2*(tp+1)*(tp+2) <= r) tp++;
  while (2*tp*(tp+1) > r) tp--;
  int rem = r - 2*tp*(tp+1);
  int qi, ki;
  if (rem < 2*tp + 2){ qi = 2*tp; ki = rem; } else { qi = 2*tp + 1; ki = rem - (2*tp + 2); }

  int l = threadIdx.x, lo = l & 15, hi = l >> 4;

  f32x4 acc[4][4];
  #pragma unroll
  for (int m = 0; m < 4; m++)
    #pragma unroll
    for (int n = 0; n < 4; n++) acc[m][n] = (f32x4){0.f,0.f,0.f,0.f};

  if (ki <= qi){
    const u16* Ap = Q + ((size_t)b*S_LEN + (size_t)qi*64 + lo) * DMODEL + hi*8;
    const u16* Bp = K + ((size_t)b*S_LEN + (size_t)ki*64 + lo) * DMODEL + hi*8;
    bf16x8 a0[4], b0[4], a1[4], b1[4];
    LOADQK(0, a0, b0);
    #pragma unroll
    for (int t2 = 0; t2 < 16; t2 += 2){
      LOADQK(t2+1, a1, b1);
      MFMA16(a0, b0);
      if (t2 + 2 < 16) LOADQK(t2+2, a0, b0);
      MFMA16(a1, b1);
    }
  }

  int qt = qi >> 1, kt = ki >> 1;
  u16* Pt = P + ((size_t)b*NPAIR + (size_t)qt*(qt+1)/2 + kt) * 16384
              + (size_t)(qi & 1) * 64 * 128 + (size_t)(ki & 1) * 64;
  #pragma unroll
  for (int m = 0; m < 4; m++){
    #pragma unroll
    for (int j = 0; j < 4; j++){
      int row = m*16 + hi*4 + j;
      int grow = qi*64 + row;
      float rsum = 0.f;
      #pragma unroll
      for (int n = 0; n < 4; n++){
        int col = n*16 + lo;
        int gcol = ki*64 + col;
        float s = (gcol > grow) ? 0.f : acc[m][n][j] * SCALE;   // masked score = 0
        u16 pb = f2bf(__expf(s));
        Pt[(size_t)row*128 + col] = pb;
        rsum += bf2f(pb);            // sum the ROUNDED value: consistent num/denom
      }
      rsum += __shfl_xor(rsum, 1);
      rsum += __shfl_xor(rsum, 2);
      rsum += __shfl_xor(rsum, 4);
      rsum += __shfl_xor(rsum, 8);
      if (lo == 0) atomicAdd(&Z[(size_t)b*S_LEN + grow], rsum);
    }
  }
}

// ---------------- PV: single-wave 64x64 all-register --------------
__global__ __launch_bounds__(64) void pv_kernel(const u16* __restrict__ P,
                                                const u16* __restrict__ Vt,
                                                const float* __restrict__ sufx,
                                                const float* __restrict__ Z,
                                                float* __restrict__ out)
{
  int flat = (blockIdx.z*64 + blockIdx.y)*8 + blockIdx.x;
  int w = (flat & 7) * 256 + (flat >> 3);        // XCD chunk swizzle (2048 = 8*256)
  int b  = w >> 9;
  int qip = (w >> 3) & 63;
  int qi  = (qip & 1) ? (qip >> 1) : 63 - (qip >> 1);   // interleave big/small per chunk
  int ci  = w & 7;
  int qt  = qi >> 1;

  int l = threadIdx.x, lo = l & 15, hi = l >> 4;

  // per-lane bases: P tile rows (stride 128 elems), Vt rows (stride S_LEN elems)
  const u16* Ap = P + ((size_t)b*NPAIR + (size_t)qt*(qt+1)/2) * 16384
                    + (size_t)(qi & 1) * 64 * 128 + (size_t)lo * 128 + hi*8;
  const u16* Bp = Vt + ((size_t)b*DMODEL + (size_t)ci*64 + lo) * S_LEN + hi*8;

  f32x4 acc[4][4];
  #pragma unroll
  for (int m = 0; m < 4; m++)
    #pragma unroll
    for (int n = 0; n < 4; n++) acc[m][n] = (f32x4){0.f,0.f,0.f,0.f};

  int nstep = (qt + 1) * 4;   // K-steps of 32 (always even)

  // stage tt: A elems + kt_*16384 + (tt&3)*32 ; B elems + tt*32
#define LOADPV(tt_, aa, bb) { int kt_ = (tt_) >> 2, s4_ = ((tt_) & 3) * 32; \
    _Pragma("unroll") \
    for (int m_ = 0; m_ < 4; m_++){ \
      aa[m_] = *(const bf16x8*)(Ap + (size_t)kt_*16384 + (size_t)m_*2048 + s4_); \
      bb[m_] = *(const bf16x8*)(Bp + (size_t)(tt_)*32 + (size_t)m_*16*S_LEN); } }

  bf16x8 a0[4], b0[4], a1[4], b1[4];
  LOADPV(0, a0, b0);
  #pragma unroll 1
  for (int t2 = 0; t2 < nstep; t2 += 2){
    LOADPV(t2+1, a1, b1);
    MFMA16(a0, b0);
    if (t2 + 2 < nstep) LOADPV(t2+2, a0, b0);
    MFMA16(a1, b1);
  }
#undef LOADPV

  float zadd = (float)(S_LEN - (qt + 1) * 128);  // future tiles contribute exp(0)=1 each
  const float* suf = sufx + ((size_t)b*NTILE + qt)*DMODEL + ci*64;
  const float* Zp  = Z + (size_t)b*S_LEN + (size_t)qi*64;
  float* O = out + ((size_t)b*S_LEN + (size_t)qi*64) * DMODEL + ci*64;
  #pragma unroll
  for (int m = 0; m < 4; m++){
    #pragma unroll
    for (int j = 0; j < 4; j++){
      int row = m*16 + hi*4 + j;
      float rz = 1.f / (Zp[row] + zadd);
      #pragma unroll
      for (int n = 0; n < 4; n++){
        int col = n*16 + lo;
        O[(size_t)row*DMODEL + col] = (acc[m][n][j] + suf[col]) * rz;
      }
    }
  }
}

// ------------------------------------------------------------------
extern "C" void kernel_launch(void* const* d_in, const int* in_sizes, int n_in,
                              void* d_out, int out_size, void* d_ws, size_t ws_size,
                              hipStream_t stream)
{
  const float* q_in = (const float*)d_in[0];
  const float* k_in = (const float*)d_in[1];
  const float* v_in = (const float*)d_in[2];
  const float* Wq   = (const float*)d_in[3];
  const float* bq   = (const float*)d_in[4];
  const float* Wk   = (const float*)d_in[5];
  const float* bk   = (const float*)d_in[6];
  const float* Wv   = (const float*)d_in[7];
  const float* bv   = (const float*)d_in[8];
  float* out = (float*)d_out;
  char*  ws  = (char*)d_ws;

  const size_t NTOK  = (size_t)NBATCH * S_LEN;       // 16384
  const size_t TEN_B = NTOK * DMODEL * 2;            // 16.8 MB bf16 tensor

  size_t off = 0;
  u16* Wq_b = (u16*)(ws + off); off += DMODEL*DMODEL*2;
  u16* Wk_b = (u16*)(ws + off); off += DMODEL*DMODEL*2;
  u16* Wv_b = (u16*)(ws + off); off += DMODEL*DMODEL*2;
  // union region: bf16 input casts (live until proj) / P tiles (after)
  size_t uoff = off;
  u16* qx = (u16*)(ws + uoff);
  u16* kx = qx + NTOK*DMODEL;
  u16* vx = kx + NTOK*DMODEL;
  u16* Pbuf = (u16*)(ws + uoff);
  size_t usize = (size_t)NBATCH * NPAIR * 16384 * 2; // 69.2 MB >= 3 casts
  off = uoff + usize;
  u16* Qb  = (u16*)(ws + off); off += TEN_B;
  u16* Kb  = (u16*)(ws + off); off += TEN_B;
  u16* Vb  = (u16*)(ws + off); off += TEN_B;
  u16* Vtb = (u16*)(ws + off); off += TEN_B;
  float* part = (float*)(ws + off); off += (size_t)NBATCH*NTILE*DMODEL*4;
  float* sufx = (float*)(ws + off); off += (size_t)NBATCH*NTILE*DMODEL*4;
  float* Zful = (float*)(ws + off); off += (size_t)NBATCH*S_LEN*4;

  int n8_big = (int)(NTOK * DMODEL / 8);   // 1048576
  int n8_w   = DMODEL * DMODEL / 8;        // 32768
  cast3_kernel<<<dim3(2048, 3), 256, 0, stream>>>(q_in, k_in, v_in, qx, kx, vx, n8_big);
  cast3_kernel<<<dim3(128, 3), 256, 0, stream>>>(Wq, Wk, Wv, Wq_b, Wk_b, Wv_b, n8_w);
  zero_kernel<<<(NBATCH*S_LEN + 255)/256, 256, 0, stream>>>(Zful, NBATCH*S_LEN);

  proj_kernel<<<dim3(DMODEL/64, (unsigned)(NTOK/64), 3), 64, 0, stream>>>(
      qx, kx, vx, Wq_b, Wk_b, Wv_b, bq, bk, bv, Qb, Kb, Vb);

  transpose_kernel<<<dim3(S_LEN/64, DMODEL/64, NBATCH), 256, 0, stream>>>(Vb, Vtb);
  vpart_kernel<<<dim3(NTILE, NBATCH), 256, 0, stream>>>(Vb, part);
  suffix_kernel<<<NBATCH, DMODEL, 0, stream>>>(part, sufx);

  score_kernel<<<8448, 64, 0, stream>>>(Qb, Kb, Pbuf, Zful);
  pv_kernel<<<dim3(8, 64, NBATCH), 64, 0, stream>>>(Pbuf, Vtb, sufx, Zful, out);
}

// Round 10
// 364.755 us; speedup vs baseline: 1.6645x; 1.6645x over previous
//
#include <hip/hip_runtime.h>

typedef unsigned short u16;
typedef unsigned int   u32;
typedef __bf16  bf16x8 __attribute__((ext_vector_type(8)));
typedef float   f32x4  __attribute__((ext_vector_type(4)));

#define S_LEN   4096
#define DMODEL  512
#define NBATCH  4
#define NTILE   32          // S/128
#define NPAIR   528         // NTILE*(NTILE+1)/2
#define SCALE   0.044194173824159216f   // 1/sqrt(512)

__device__ __forceinline__ u16 f2bf(float x){
  u32 u = __float_as_uint(x);
  return (u16)((u + 0x7fffu + ((u >> 16) & 1u)) >> 16);   // RNE
}
__device__ __forceinline__ float bf2f(u16 u){ return __uint_as_float(((u32)u) << 16); }

__device__ __forceinline__ void gload_lds16(const void* g, void* l){
  __builtin_amdgcn_global_load_lds((const __attribute__((address_space(1))) void*)g,
                                   (__attribute__((address_space(3))) void*)l, 16, 0, 0);
}

// ---- shared 128x128x(K) NT-GEMM machinery: 4 waves, BK=32, 2-phase dbuf ----
// LDS linear [128 rows][32 elems]; XOR-swizzle on SOURCE chunk + READ chunk
// (chunk = 16B = 8 elems; phys chunk c holds logical chunk c^(row&3)).
// Each wave stages 2x16 rows of A and B per tile: 4 gload_lds -> vmcnt(4).

#define STAGE_TILE(Asrc, lda, Bsrc, ldb, buf) { \
  _Pragma("unroll") \
  for (int cc_ = 0; cc_ < 2; ++cc_){ \
    int c_ = w + cc_*4; \
    int r_ = c_*16 + srow; \
    int sw_ = (scol ^ (r_ & 3)) * 8; \
    gload_lds16((Asrc) + (size_t)r_*(lda) + sw_, ldsA + (buf)*4096 + c_*512); \
    gload_lds16((Bsrc) + (size_t)r_*(ldb) + sw_, ldsB + (buf)*4096 + c_*512); \
  } }

#define READ_FRAGS(buf) { \
  _Pragma("unroll") \
  for (int m_ = 0; m_ < 4; m_++){ \
    int rA_ = wr*64 + m_*16 + lo; \
    fa[m_] = *(const bf16x8*)(ldsA + (buf)*4096 + rA_*32 + ((hi ^ (rA_ & 3)) * 8)); \
    int rB_ = wc*64 + m_*16 + lo; \
    fb[m_] = *(const bf16x8*)(ldsB + (buf)*4096 + rB_*32 + ((hi ^ (rB_ & 3)) * 8)); \
  } }

#define MFMA16() { _Pragma("unroll") \
  for (int m_ = 0; m_ < 4; m_++){ _Pragma("unroll") \
    for (int n_ = 0; n_ < 4; n_++) \
      acc[m_][n_] = __builtin_amdgcn_mfma_f32_16x16x32_bf16(fa[m_], fb[n_], acc[m_][n_], 0, 0, 0); } }

#define PHASE_WAIT(cond_more) \
  if (cond_more) { asm volatile("s_waitcnt vmcnt(4)" ::: "memory"); } \
  else           { asm volatile("s_waitcnt vmcnt(0)" ::: "memory"); } \
  __builtin_amdgcn_s_barrier(); \
  __builtin_amdgcn_sched_barrier(0);

#define PHASE_END() \
  __builtin_amdgcn_s_barrier(); \
  __builtin_amdgcn_sched_barrier(0);

// ---------------- casts f32 -> bf16 (3 tensors per launch) --------
__global__ __launch_bounds__(256) void cast3_kernel(const float* __restrict__ a,
                                                    const float* __restrict__ b,
                                                    const float* __restrict__ c,
                                                    u16* oa, u16* ob, u16* oc, int n8){
  int z = blockIdx.y;
  const float* in = (z == 0) ? a : (z == 1) ? b : c;
  u16* out = (z == 0) ? oa : (z == 1) ? ob : oc;
  int i = blockIdx.x * 256 + threadIdx.x;
  int stride = gridDim.x * 256;
  for (; i < n8; i += stride){
    const float4* p = (const float4*)in + (size_t)i * 2;
    float4 x = p[0], y = p[1];
    ushort4 o0 = make_ushort4(f2bf(x.x), f2bf(x.y), f2bf(x.z), f2bf(x.w));
    ushort4 o1 = make_ushort4(f2bf(y.x), f2bf(y.y), f2bf(y.z), f2bf(y.w));
    ((ushort4*)out)[(size_t)i*2]   = o0;
    ((ushort4*)out)[(size_t)i*2+1] = o1;
  }
}

__global__ __launch_bounds__(256) void zero_kernel(float* __restrict__ p, int n){
  int i = blockIdx.x * 256 + threadIdx.x;
  if (i < n) p[i] = 0.f;
}

// ---------------- projections: Y = X * W^T + bias (merged) --------
__global__ __launch_bounds__(256) void proj_kernel(
    const u16* __restrict__ qx, const u16* __restrict__ kx, const u16* __restrict__ vx,
    const u16* __restrict__ Wq, const u16* __restrict__ Wk, const u16* __restrict__ Wv,
    const float* __restrict__ bq, const float* __restrict__ bk, const float* __restrict__ bv,
    u16* Qb, u16* Kb, u16* Vb)
{
  __shared__ __align__(16) u16 ldsA[8192], ldsB[8192];
  int z = blockIdx.z;
  const u16* X = (z==0) ? qx : (z==1) ? kx : vx;
  const u16* W = (z==0) ? Wq : (z==1) ? Wk : Wv;
  const float* bias = (z==0) ? bq : (z==1) ? bk : bv;
  u16* Y = (z==0) ? Qb : (z==1) ? Kb : Vb;

  int cn = blockIdx.x, rm = blockIdx.y;
  int t = threadIdx.x, w = t >> 6, l = t & 63, wr = w >> 1, wc = w & 1;
  int srow = l >> 2, scol = l & 3, lo = l & 15, hi = l >> 4;

  f32x4 acc[4][4];
  #pragma unroll
  for (int m = 0; m < 4; m++)
    #pragma unroll
    for (int n = 0; n < 4; n++) acc[m][n] = (f32x4){0.f,0.f,0.f,0.f};
  bf16x8 fa[4], fb[4];

  const u16* A = X + (size_t)rm * 128 * DMODEL;
  const u16* B = W + (size_t)cn * 128 * DMODEL;

  STAGE_TILE(A, DMODEL, B, DMODEL, 0);
  for (int s = 0; s < 16; ++s){
    int cur = s & 1;
    if (s + 1 < 16) STAGE_TILE(A + (s+1)*32, DMODEL, B + (s+1)*32, DMODEL, cur ^ 1)
    PHASE_WAIT(s + 1 < 16)
    READ_FRAGS(cur)
    MFMA16()
    PHASE_END()
  }

  #pragma unroll
  for (int n = 0; n < 4; n++){
    int col = cn*128 + wc*64 + n*16 + lo;
    float bs = bias[col];
    #pragma unroll
    for (int m = 0; m < 4; m++){
      int row0 = rm*128 + wr*64 + m*16 + hi*4;
      #pragma unroll
      for (int j = 0; j < 4; j++)
        Y[(size_t)(row0 + j) * DMODEL + col] = f2bf(acc[m][n][j] + bs);
    }
  }
}

// ---------------- V transpose -------------------------------------
__global__ __launch_bounds__(256) void transpose_kernel(const u16* __restrict__ V,
                                                        u16* __restrict__ Vt)
{
  __shared__ u16 tile[64][66];
  int k0 = blockIdx.x * 64, c0 = blockIdx.y * 64, b = blockIdx.z;
  int t = threadIdx.x;
  #pragma unroll
  for (int i = 0; i < 16; i++){
    int idx = i*256 + t; int r = idx >> 6, c = idx & 63;
    tile[r][c] = V[((size_t)b*S_LEN + k0 + r) * DMODEL + c0 + c];
  }
  __syncthreads();
  #pragma unroll
  for (int i = 0; i < 16; i++){
    int idx = i*256 + t; int r = idx >> 6, c = idx & 63;
    Vt[((size_t)b*DMODEL + c0 + r) * S_LEN + k0 + c] = tile[c][r];
  }
}

// ---------------- V per-tile column sums + suffix scan ------------
__global__ __launch_bounds__(256) void vpart_kernel(const u16* __restrict__ V,
                                                    float* __restrict__ part){
  int t = blockIdx.x, b = blockIdx.y, c = threadIdx.x;
  const u16* base = V + ((size_t)b*S_LEN + t*128) * DMODEL;
  float s0 = 0.f, s1 = 0.f;
  for (int k = 0; k < 128; k++){
    s0 += bf2f(base[(size_t)k*DMODEL + c]);
    s1 += bf2f(base[(size_t)k*DMODEL + 256 + c]);
  }
  part[((size_t)b*NTILE + t)*DMODEL + c]       = s0;
  part[((size_t)b*NTILE + t)*DMODEL + 256 + c] = s1;
}

__global__ void suffix_kernel(const float* __restrict__ part, float* __restrict__ sufx){
  int b = blockIdx.x, c = threadIdx.x;
  float s = 0.f;
  for (int t = NTILE - 1; t >= 0; t--){
    sufx[((size_t)b*NTILE + t)*DMODEL + c] = s;
    s += part[((size_t)b*NTILE + t)*DMODEL + c];
  }
}

// ---------------- score: P = exp(mask(Q K^T * scale)), Z += rowsums
__global__ __launch_bounds__(256) void score_kernel(const u16* __restrict__ Q,
                                                    const u16* __restrict__ K,
                                                    u16* __restrict__ P,
                                                    float* __restrict__ Z)
{
  __shared__ __align__(16) u16 ldsA[8192], ldsB[8192];
  int p = blockIdx.x, b = blockIdx.y;
  int qt = (int)((sqrtf(8.f*p + 1.f) - 1.f) * 0.5f);
  while ((qt+1)*(qt+2)/2 <= p) qt++;
  while (qt*(qt+1)/2 > p) qt--;
  int kt = p - qt*(qt+1)/2;

  int t = threadIdx.x, w = t >> 6, l = t & 63, wr = w >> 1, wc = w & 1;
  int srow = l >> 2, scol = l & 3, lo = l & 15, hi = l >> 4;

  f32x4 acc[4][4];
  #pragma unroll
  for (int m = 0; m < 4; m++)
    #pragma unroll
    for (int n = 0; n < 4; n++) acc[m][n] = (f32x4){0.f,0.f,0.f,0.f};
  bf16x8 fa[4], fb[4];

  const u16* A = Q + ((size_t)b*S_LEN + (size_t)qt*128) * DMODEL;
  const u16* B = K + ((size_t)b*S_LEN + (size_t)kt*128) * DMODEL;

  STAGE_TILE(A, DMODEL, B, DMODEL, 0);
  for (int s = 0; s < 16; ++s){
    int cur = s & 1;
    if (s + 1 < 16) STAGE_TILE(A + (s+1)*32, DMODEL, B + (s+1)*32, DMODEL, cur ^ 1)
    PHASE_WAIT(s + 1 < 16)
    READ_FRAGS(cur)
    MFMA16()
    PHASE_END()
  }

  u16* Pt = P + ((size_t)b*NPAIR + (size_t)qt*(qt+1)/2 + kt) * 16384;
  bool diag = (qt == kt);
  #pragma unroll
  for (int m = 0; m < 4; m++){
    #pragma unroll
    for (int j = 0; j < 4; j++){
      int rl = wr*64 + m*16 + hi*4 + j;
      float rsum = 0.f;
      #pragma unroll
      for (int n = 0; n < 4; n++){
        int cl = wc*64 + n*16 + lo;
        float s = (diag && cl > rl) ? 0.f : acc[m][n][j] * SCALE;  // masked: score 0
        u16 pb = f2bf(__expf(s));
        Pt[(size_t)rl*128 + cl] = pb;
        rsum += bf2f(pb);               // sum ROUNDED values: consistent num/denom
      }
      rsum += __shfl_xor(rsum, 1);
      rsum += __shfl_xor(rsum, 2);
      rsum += __shfl_xor(rsum, 4);
      rsum += __shfl_xor(rsum, 8);
      if (lo == 0) atomicAdd(&Z[(size_t)b*S_LEN + qt*128 + rl], rsum);
    }
  }
}

// ---------------- PV: out = (P·V + suffix) / (Z + count) ----------
__global__ __launch_bounds__(256) void pv_kernel(const u16* __restrict__ P,
                                                 const u16* __restrict__ Vt,
                                                 const float* __restrict__ sufx,
                                                 const float* __restrict__ Z,
                                                 float* __restrict__ out)
{
  __shared__ __align__(16) u16 ldsA[8192], ldsB[8192];
  int ci = blockIdx.x, qt = (NTILE - 1) - blockIdx.y, b = blockIdx.z;  // big first
  int t = threadIdx.x, w = t >> 6, l = t & 63, wr = w >> 1, wc = w & 1;
  int srow = l >> 2, scol = l & 3, lo = l & 15, hi = l >> 4;

  f32x4 acc[4][4];
  #pragma unroll
  for (int m = 0; m < 4; m++)
    #pragma unroll
    for (int n = 0; n < 4; n++) acc[m][n] = (f32x4){0.f,0.f,0.f,0.f};
  bf16x8 fa[4], fb[4];

  const u16* Abase = P + ((size_t)b*NPAIR + (size_t)qt*(qt+1)/2) * 16384;
  const u16* Bbase = Vt + ((size_t)b*DMODEL + (size_t)ci*128) * S_LEN;

  int T = (qt + 1) * 4;   // 32-K steps

#define PV_A(tt) (Abase + (size_t)((tt) >> 2)*16384 + ((tt) & 3)*32)
#define PV_B(tt) (Bbase + (size_t)(tt)*32)

  STAGE_TILE(PV_A(0), 128, PV_B(0), S_LEN, 0);
  for (int s = 0; s < T; ++s){
    int cur = s & 1;
    if (s + 1 < T) STAGE_TILE(PV_A(s+1), 128, PV_B(s+1), S_LEN, cur ^ 1)
    PHASE_WAIT(s + 1 < T)
    READ_FRAGS(cur)
    MFMA16()
    PHASE_END()
  }
#undef PV_A
#undef PV_B

  float zadd = (float)(S_LEN - (qt + 1) * 128);  // future keys contribute exp(0)=1
  const float* suf = sufx + ((size_t)b*NTILE + qt)*DMODEL + ci*128;
  const float* Zp  = Z + (size_t)b*S_LEN + (size_t)qt*128;
  float* O = out + ((size_t)b*S_LEN + (size_t)qt*128) * DMODEL + ci*128;
  #pragma unroll
  for (int m = 0; m < 4; m++){
    #pragma unroll
    for (int j = 0; j < 4; j++){
      int row = wr*64 + m*16 + hi*4 + j;
      float rz = 1.f / (Zp[row] + zadd);
      #pragma unroll
      for (int n = 0; n < 4; n++){
        int col = wc*64 + n*16 + lo;
        O[(size_t)row*DMODEL + col] = (acc[m][n][j] + suf[col]) * rz;
      }
    }
  }
}

// ------------------------------------------------------------------
extern "C" void kernel_launch(void* const* d_in, const int* in_sizes, int n_in,
                              void* d_out, int out_size, void* d_ws, size_t ws_size,
                              hipStream_t stream)
{
  const float* q_in = (const float*)d_in[0];
  const float* k_in = (const float*)d_in[1];
  const float* v_in = (const float*)d_in[2];
  const float* Wq   = (const float*)d_in[3];
  const float* bq   = (const float*)d_in[4];
  const float* Wk   = (const float*)d_in[5];
  const float* bk   = (const float*)d_in[6];
  const float* Wv   = (const float*)d_in[7];
  const float* bv   = (const float*)d_in[8];
  float* out = (float*)d_out;
  char*  ws  = (char*)d_ws;

  const size_t NTOK  = (size_t)NBATCH * S_LEN;       // 16384
  const size_t TEN_B = NTOK * DMODEL * 2;            // 16.8 MB bf16 tensor

  size_t off = 0;
  u16* Wq_b = (u16*)(ws + off); off += DMODEL*DMODEL*2;
  u16* Wk_b = (u16*)(ws + off); off += DMODEL*DMODEL*2;
  u16* Wv_b = (u16*)(ws + off); off += DMODEL*DMODEL*2;
  // union region: bf16 input casts (live until proj) / P tiles (after)
  size_t uoff = off;
  u16* qx = (u16*)(ws + uoff);
  u16* kx = qx + NTOK*DMODEL;
  u16* vx = kx + NTOK*DMODEL;
  u16* Pbuf = (u16*)(ws + uoff);
  size_t usize = (size_t)NBATCH * NPAIR * 16384 * 2; // 69.2 MB >= 3 casts
  off = uoff + usize;
  u16* Qb  = (u16*)(ws + off); off += TEN_B;
  u16* Kb  = (u16*)(ws + off); off += TEN_B;
  u16* Vb  = (u16*)(ws + off); off += TEN_B;
  u16* Vtb = (u16*)(ws + off); off += TEN_B;
  float* part = (float*)(ws + off); off += (size_t)NBATCH*NTILE*DMODEL*4;
  float* sufx = (float*)(ws + off); off += (size_t)NBATCH*NTILE*DMODEL*4;
  float* Zful = (float*)(ws + off); off += (size_t)NBATCH*S_LEN*4;

  int n8_big = (int)(NTOK * DMODEL / 8);   // 1048576
  int n8_w   = DMODEL * DMODEL / 8;        // 32768
  cast3_kernel<<<dim3(2048, 3), 256, 0, stream>>>(q_in, k_in, v_in, qx, kx, vx, n8_big);
  cast3_kernel<<<dim3(128, 3), 256, 0, stream>>>(Wq, Wk, Wv, Wq_b, Wk_b, Wv_b, n8_w);
  zero_kernel<<<(NBATCH*S_LEN + 255)/256, 256, 0, stream>>>(Zful, NBATCH*S_LEN);

  proj_kernel<<<dim3(DMODEL/128, (unsigned)(NTOK/128), 3), 256, 0, stream>>>(
      qx, kx, vx, Wq_b, Wk_b, Wv_b, bq, bk, bv, Qb, Kb, Vb);

  transpose_kernel<<<dim3(S_LEN/64, DMODEL/64, NBATCH), 256, 0, stream>>>(Vb, Vtb);
  vpart_kernel<<<dim3(NTILE, NBATCH), 256, 0, stream>>>(Vb, part);
  suffix_kernel<<<NBATCH, DMODEL, 0, stream>>>(part, sufx);

  score_kernel<<<dim3(NPAIR, NBATCH), 256, 0, stream>>>(Qb, Kb, Pbuf, Zful);
  pv_kernel<<<dim3(DMODEL/128, NTILE, NBATCH), 256, 0, stream>>>(Pbuf, Vtb, sufx, Zful, out);
}

// Round 11
// 360.305 us; speedup vs baseline: 1.6850x; 1.0123x over previous
//
#include <hip/hip_runtime.h>

typedef unsigned short u16;
typedef unsigned int   u32;
typedef __bf16  bf16x8 __attribute__((ext_vector_type(8)));
typedef float   f32x4  __attribute__((ext_vector_type(4)));

#define S_LEN   4096
#define DMODEL  512
#define NBATCH  4
#define NTILE   32          // S/128
#define NPAIR   528         // NTILE*(NTILE+1)/2
#define SCALE   0.044194173824159216f   // 1/sqrt(512)

__device__ __forceinline__ u16 f2bf(float x){
  u32 u = __float_as_uint(x);
  return (u16)((u + 0x7fffu + ((u >> 16) & 1u)) >> 16);   // RNE
}
__device__ __forceinline__ float bf2f(u16 u){ return __uint_as_float(((u32)u) << 16); }

__device__ __forceinline__ void gload_lds16(const void* g, void* l){
  __builtin_amdgcn_global_load_lds((const __attribute__((address_space(1))) void*)g,
                                   (__attribute__((address_space(3))) void*)l, 16, 0, 0);
}

// ---- 128x128xK NT-GEMM machinery: 4 waves, BK=32, 3-buffer 2-deep pipe ----
// LDS [3 bufs][128 rows][32 elems]; source/read chunk XOR swizzle (validated R10).
// Each wave stages 2x16 rows of A and B per tile: 4 gload_lds per thread.
// vmcnt ladder: 2 tiles in flight -> wait vmcnt(16); 1 -> (8); last -> (0).

#define STAGE_TILE(Asrc, lda, Bsrc, ldb, buf) { \
  _Pragma("unroll") \
  for (int cc_ = 0; cc_ < 2; ++cc_){ \
    int c_ = w + cc_*4; \
    int r_ = c_*16 + srow; \
    int sw_ = (scol ^ (r_ & 3)) * 8; \
    gload_lds16((Asrc) + (size_t)r_*(lda) + sw_, ldsA + (buf)*4096 + c_*512); \
    gload_lds16((Bsrc) + (size_t)r_*(ldb) + sw_, ldsB + (buf)*4096 + c_*512); \
  } }

#define READ_FRAGS(buf) { \
  _Pragma("unroll") \
  for (int m_ = 0; m_ < 4; m_++){ \
    int rA_ = wr*64 + m_*16 + lo; \
    fa[m_] = *(const bf16x8*)(ldsA + (buf)*4096 + rA_*32 + ((hi ^ (rA_ & 3)) * 8)); \
    int rB_ = wc*64 + m_*16 + lo; \
    fb[m_] = *(const bf16x8*)(ldsB + (buf)*4096 + rB_*32 + ((hi ^ (rB_ & 3)) * 8)); \
  } }

#define MFMA16() { _Pragma("unroll") \
  for (int m_ = 0; m_ < 4; m_++){ _Pragma("unroll") \
    for (int n_ = 0; n_ < 4; n_++) \
      acc[m_][n_] = __builtin_amdgcn_mfma_f32_16x16x32_bf16(fa[m_], fb[n_], acc[m_][n_], 0, 0, 0); } }

#define PIPE_WAIT(t_, T_) \
  if ((t_) + 2 < (T_))      { asm volatile("s_waitcnt vmcnt(16)" ::: "memory"); } \
  else if ((t_) + 1 < (T_)) { asm volatile("s_waitcnt vmcnt(8)"  ::: "memory"); } \
  else                      { asm volatile("s_waitcnt vmcnt(0)"  ::: "memory"); } \
  __builtin_amdgcn_s_barrier(); \
  __builtin_amdgcn_sched_barrier(0);

#define PHASE_END() \
  __builtin_amdgcn_s_barrier(); \
  __builtin_amdgcn_sched_barrier(0);

#define ROT3(v_) v_ = ((v_) == 2) ? 0 : (v_) + 1;

// ---------------- casts f32 -> bf16 (3 tensors per launch) --------
__global__ __launch_bounds__(256) void cast3_kernel(const float* __restrict__ a,
                                                    const float* __restrict__ b,
                                                    const float* __restrict__ c,
                                                    u16* oa, u16* ob, u16* oc, int n8){
  int z = blockIdx.y;
  const float* in = (z == 0) ? a : (z == 1) ? b : c;
  u16* out = (z == 0) ? oa : (z == 1) ? ob : oc;
  int i = blockIdx.x * 256 + threadIdx.x;
  int stride = gridDim.x * 256;
  for (; i < n8; i += stride){
    const float4* p = (const float4*)in + (size_t)i * 2;
    float4 x = p[0], y = p[1];
    ushort4 o0 = make_ushort4(f2bf(x.x), f2bf(x.y), f2bf(x.z), f2bf(x.w));
    ushort4 o1 = make_ushort4(f2bf(y.x), f2bf(y.y), f2bf(y.z), f2bf(y.w));
    ((ushort4*)out)[(size_t)i*2]   = o0;
    ((ushort4*)out)[(size_t)i*2+1] = o1;
  }
}

__global__ __launch_bounds__(256) void zero_kernel(float* __restrict__ p, int n){
  int i = blockIdx.x * 256 + threadIdx.x;
  if (i < n) p[i] = 0.f;
}

// ---------------- projections: Y = X * W^T + bias (merged) --------
__global__ __launch_bounds__(256) void proj_kernel(
    const u16* __restrict__ qx, const u16* __restrict__ kx, const u16* __restrict__ vx,
    const u16* __restrict__ Wq, const u16* __restrict__ Wk, const u16* __restrict__ Wv,
    const float* __restrict__ bq, const float* __restrict__ bk, const float* __restrict__ bv,
    u16* Qb, u16* Kb, u16* Vb)
{
  __shared__ __align__(16) u16 ldsA[12288], ldsB[12288];
  int z = blockIdx.z;
  const u16* X = (z==0) ? qx : (z==1) ? kx : vx;
  const u16* W = (z==0) ? Wq : (z==1) ? Wk : Wv;
  const float* bias = (z==0) ? bq : (z==1) ? bk : bv;
  u16* Y = (z==0) ? Qb : (z==1) ? Kb : Vb;

  int cn = blockIdx.x, rm = blockIdx.y;
  int t = threadIdx.x, w = t >> 6, l = t & 63, wr = w >> 1, wc = w & 1;
  int srow = l >> 2, scol = l & 3, lo = l & 15, hi = l >> 4;

  f32x4 acc[4][4];
  #pragma unroll
  for (int m = 0; m < 4; m++)
    #pragma unroll
    for (int n = 0; n < 4; n++) acc[m][n] = (f32x4){0.f,0.f,0.f,0.f};
  bf16x8 fa[4], fb[4];

  const u16* A = X + (size_t)rm * 128 * DMODEL;
  const u16* B = W + (size_t)cn * 128 * DMODEL;

  STAGE_TILE(A, DMODEL, B, DMODEL, 0);
  STAGE_TILE(A + 32, DMODEL, B + 32, DMODEL, 1);
  int cur = 0, nx2 = 2;
  for (int s = 0; s < 16; ++s){
    if (s + 2 < 16) STAGE_TILE(A + (s+2)*32, DMODEL, B + (s+2)*32, DMODEL, nx2)
    PIPE_WAIT(s, 16)
    READ_FRAGS(cur)
    MFMA16()
    PHASE_END()
    ROT3(cur) ROT3(nx2)
  }

  #pragma unroll
  for (int n = 0; n < 4; n++){
    int col = cn*128 + wc*64 + n*16 + lo;
    float bs = bias[col];
    #pragma unroll
    for (int m = 0; m < 4; m++){
      int row0 = rm*128 + wr*64 + m*16 + hi*4;
      #pragma unroll
      for (int j = 0; j < 4; j++)
        Y[(size_t)(row0 + j) * DMODEL + col] = f2bf(acc[m][n][j] + bs);
    }
  }
}

// ---------------- V transpose -------------------------------------
__global__ __launch_bounds__(256) void transpose_kernel(const u16* __restrict__ V,
                                                        u16* __restrict__ Vt)
{
  __shared__ u16 tile[64][66];
  int k0 = blockIdx.x * 64, c0 = blockIdx.y * 64, b = blockIdx.z;
  int t = threadIdx.x;
  #pragma unroll
  for (int i = 0; i < 16; i++){
    int idx = i*256 + t; int r = idx >> 6, c = idx & 63;
    tile[r][c] = V[((size_t)b*S_LEN + k0 + r) * DMODEL + c0 + c];
  }
  __syncthreads();
  #pragma unroll
  for (int i = 0; i < 16; i++){
    int idx = i*256 + t; int r = idx >> 6, c = idx & 63;
    Vt[((size_t)b*DMODEL + c0 + r) * S_LEN + k0 + c] = tile[c][r];
  }
}

// ---------------- V per-tile column sums + suffix scan ------------
__global__ __launch_bounds__(256) void vpart_kernel(const u16* __restrict__ V,
                                                    float* __restrict__ part){
  int t = blockIdx.x, b = blockIdx.y, c = threadIdx.x;
  const u16* base = V + ((size_t)b*S_LEN + t*128) * DMODEL;
  float s0 = 0.f, s1 = 0.f;
  for (int k = 0; k < 128; k++){
    s0 += bf2f(base[(size_t)k*DMODEL + c]);
    s1 += bf2f(base[(size_t)k*DMODEL + 256 + c]);
  }
  part[((size_t)b*NTILE + t)*DMODEL + c]       = s0;
  part[((size_t)b*NTILE + t)*DMODEL + 256 + c] = s1;
}

__global__ void suffix_kernel(const float* __restrict__ part, float* __restrict__ sufx){
  int b = blockIdx.x, c = threadIdx.x;
  float s = 0.f;
  for (int t = NTILE - 1; t >= 0; t--){
    sufx[((size_t)b*NTILE + t)*DMODEL + c] = s;
    s += part[((size_t)b*NTILE + t)*DMODEL + c];
  }
}

// ---------------- score: P = exp(mask(Q K^T * scale)), Z += rowsums
__global__ __launch_bounds__(256) void score_kernel(const u16* __restrict__ Q,
                                                    const u16* __restrict__ K,
                                                    u16* __restrict__ P,
                                                    float* __restrict__ Z)
{
  __shared__ __align__(16) u16 ldsA[12288], ldsB[12288];
  int p = blockIdx.x, b = blockIdx.y;
  int qt = (int)((sqrtf(8.f*p + 1.f) - 1.f) * 0.5f);
  while ((qt+1)*(qt+2)/2 <= p) qt++;
  while (qt*(qt+1)/2 > p) qt--;
  int kt = p - qt*(qt+1)/2;

  int t = threadIdx.x, w = t >> 6, l = t & 63, wr = w >> 1, wc = w & 1;
  int srow = l >> 2, scol = l & 3, lo = l & 15, hi = l >> 4;

  f32x4 acc[4][4];
  #pragma unroll
  for (int m = 0; m < 4; m++)
    #pragma unroll
    for (int n = 0; n < 4; n++) acc[m][n] = (f32x4){0.f,0.f,0.f,0.f};
  bf16x8 fa[4], fb[4];

  const u16* A = Q + ((size_t)b*S_LEN + (size_t)qt*128) * DMODEL;
  const u16* B = K + ((size_t)b*S_LEN + (size_t)kt*128) * DMODEL;

  STAGE_TILE(A, DMODEL, B, DMODEL, 0);
  STAGE_TILE(A + 32, DMODEL, B + 32, DMODEL, 1);
  int cur = 0, nx2 = 2;
  for (int s = 0; s < 16; ++s){
    if (s + 2 < 16) STAGE_TILE(A + (s+2)*32, DMODEL, B + (s+2)*32, DMODEL, nx2)
    PIPE_WAIT(s, 16)
    READ_FRAGS(cur)
    MFMA16()
    PHASE_END()
    ROT3(cur) ROT3(nx2)
  }

  u16* Pt = P + ((size_t)b*NPAIR + (size_t)qt*(qt+1)/2 + kt) * 16384;
  bool diag = (qt == kt);
  #pragma unroll
  for (int m = 0; m < 4; m++){
    #pragma unroll
    for (int j = 0; j < 4; j++){
      int rl = wr*64 + m*16 + hi*4 + j;
      float rsum = 0.f;
      #pragma unroll
      for (int n = 0; n < 4; n++){
        int cl = wc*64 + n*16 + lo;
        float s = (diag && cl > rl) ? 0.f : acc[m][n][j] * SCALE;  // masked: score 0
        u16 pb = f2bf(__expf(s));
        Pt[(size_t)rl*128 + cl] = pb;
        rsum += bf2f(pb);               // sum ROUNDED values: consistent num/denom
      }
      rsum += __shfl_xor(rsum, 1);
      rsum += __shfl_xor(rsum, 2);
      rsum += __shfl_xor(rsum, 4);
      rsum += __shfl_xor(rsum, 8);
      if (lo == 0) atomicAdd(&Z[(size_t)b*S_LEN + qt*128 + rl], rsum);
    }
  }
}

// ---------------- PV: out = (P·V + suffix) / (Z + count) ----------
// Block remap: XCD x = flat&7 gets the 4 ci-blocks of each of its (b,qt)
// groups contiguously (P-panel L2 locality) with big/small qt pairing.
__global__ __launch_bounds__(256) void pv_kernel(const u16* __restrict__ P,
                                                 const u16* __restrict__ Vt,
                                                 const float* __restrict__ sufx,
                                                 const float* __restrict__ Z,
                                                 float* __restrict__ out)
{
  __shared__ __align__(16) u16 ldsA[12288], ldsB[12288];
  int flat = blockIdx.x;
  int x    = flat & 7;           // XCD (blockIdx % 8 round-robin)
  int pnum = flat >> 3;          // slot within XCD: 0..63
  int posg = pnum >> 2;          // group position 0..15 in dispatch order
  int ci   = pnum & 3;           // 4 ci blocks contiguous -> same XCD, same time
  int rank = (posg < 8) ? posg : 23 - posg;   // pair big (rank r) w/ small (15-r)
  int qtsel = 3 - (rank >> 2);
  int qt   = x + 8*qtsel;        // big qt dispatched first
  int b    = rank & 3;

  int t = threadIdx.x, w = t >> 6, l = t & 63, wr = w >> 1, wc = w & 1;
  int srow = l >> 2, scol = l & 3, lo = l & 15, hi = l >> 4;

  f32x4 acc[4][4];
  #pragma unroll
  for (int m = 0; m < 4; m++)
    #pragma unroll
    for (int n = 0; n < 4; n++) acc[m][n] = (f32x4){0.f,0.f,0.f,0.f};
  bf16x8 fa[4], fb[4];

  const u16* Abase = P + ((size_t)b*NPAIR + (size_t)qt*(qt+1)/2) * 16384;
  const u16* Bbase = Vt + ((size_t)b*DMODEL + (size_t)ci*128) * S_LEN;

  int T = (qt + 1) * 4;   // 32-K steps (>= 4)

#define PV_A(tt) (Abase + (size_t)((tt) >> 2)*16384 + ((tt) & 3)*32)
#define PV_B(tt) (Bbase + (size_t)(tt)*32)

  STAGE_TILE(PV_A(0), 128, PV_B(0), S_LEN, 0);
  STAGE_TILE(PV_A(1), 128, PV_B(1), S_LEN, 1);
  int cur = 0, nx2 = 2;
  for (int s = 0; s < T; ++s){
    if (s + 2 < T) STAGE_TILE(PV_A(s+2), 128, PV_B(s+2), S_LEN, nx2)
    PIPE_WAIT(s, T)
    READ_FRAGS(cur)
    MFMA16()
    PHASE_END()
    ROT3(cur) ROT3(nx2)
  }
#undef PV_A
#undef PV_B

  float zadd = (float)(S_LEN - (qt + 1) * 128);  // future keys contribute exp(0)=1
  const float* suf = sufx + ((size_t)b*NTILE + qt)*DMODEL + ci*128;
  const float* Zp  = Z + (size_t)b*S_LEN + (size_t)qt*128;
  float* O = out + ((size_t)b*S_LEN + (size_t)qt*128) * DMODEL + ci*128;
  #pragma unroll
  for (int m = 0; m < 4; m++){
    #pragma unroll
    for (int j = 0; j < 4; j++){
      int row = wr*64 + m*16 + hi*4 + j;
      float rz = 1.f / (Zp[row] + zadd);
      #pragma unroll
      for (int n = 0; n < 4; n++){
        int col = wc*64 + n*16 + lo;
        O[(size_t)row*DMODEL + col] = (acc[m][n][j] + suf[col]) * rz;
      }
    }
  }
}

// ------------------------------------------------------------------
extern "C" void kernel_launch(void* const* d_in, const int* in_sizes, int n_in,
                              void* d_out, int out_size, void* d_ws, size_t ws_size,
                              hipStream_t stream)
{
  const float* q_in = (const float*)d_in[0];
  const float* k_in = (const float*)d_in[1];
  const float* v_in = (const float*)d_in[2];
  const float* Wq   = (const float*)d_in[3];
  const float* bq   = (const float*)d_in[4];
  const float* Wk   = (const float*)d_in[5];
  const float* bk   = (const float*)d_in[6];
  const float* Wv   = (const float*)d_in[7];
  const float* bv   = (const float*)d_in[8];
  float* out = (float*)d_out;
  char*  ws  = (char*)d_ws;

  const size_t NTOK  = (size_t)NBATCH * S_LEN;       // 16384
  const size_t TEN_B = NTOK * DMODEL * 2;            // 16.8 MB bf16 tensor

  size_t off = 0;
  u16* Wq_b = (u16*)(ws + off); off += DMODEL*DMODEL*2;
  u16* Wk_b = (u16*)(ws + off); off += DMODEL*DMODEL*2;
  u16* Wv_b = (u16*)(ws + off); off += DMODEL*DMODEL*2;
  // union region: bf16 input casts (live until proj) / P tiles (after)
  size_t uoff = off;
  u16* qx = (u16*)(ws + uoff);
  u16* kx = qx + NTOK*DMODEL;
  u16* vx = kx + NTOK*DMODEL;
  u16* Pbuf = (u16*)(ws + uoff);
  size_t usize = (size_t)NBATCH * NPAIR * 16384 * 2; // 69.2 MB >= 3 casts
  off = uoff + usize;
  u16* Qb  = (u16*)(ws + off); off += TEN_B;
  u16* Kb  = (u16*)(ws + off); off += TEN_B;
  u16* Vb  = (u16*)(ws + off); off += TEN_B;
  u16* Vtb = (u16*)(ws + off); off += TEN_B;
  float* part = (float*)(ws + off); off += (size_t)NBATCH*NTILE*DMODEL*4;
  float* sufx = (float*)(ws + off); off += (size_t)NBATCH*NTILE*DMODEL*4;
  float* Zful = (float*)(ws + off); off += (size_t)NBATCH*S_LEN*4;

  int n8_big = (int)(NTOK * DMODEL / 8);   // 1048576
  int n8_w   = DMODEL * DMODEL / 8;        // 32768
  cast3_kernel<<<dim3(2048, 3), 256, 0, stream>>>(q_in, k_in, v_in, qx, kx, vx, n8_big);
  cast3_kernel<<<dim3(128, 3), 256, 0, stream>>>(Wq, Wk, Wv, Wq_b, Wk_b, Wv_b, n8_w);
  zero_kernel<<<(NBATCH*S_LEN + 255)/256, 256, 0, stream>>>(Zful, NBATCH*S_LEN);

  proj_kernel<<<dim3(DMODEL/128, (unsigned)(NTOK/128), 3), 256, 0, stream>>>(
      qx, kx, vx, Wq_b, Wk_b, Wv_b, bq, bk, bv, Qb, Kb, Vb);

  transpose_kernel<<<dim3(S_LEN/64, DMODEL/64, NBATCH), 256, 0, stream>>>(Vb, Vtb);
  vpart_kernel<<<dim3(NTILE, NBATCH), 256, 0, stream>>>(Vb, part);
  suffix_kernel<<<NBATCH, DMODEL, 0, stream>>>(part, sufx);

  score_kernel<<<dim3(NPAIR, NBATCH), 256, 0, stream>>>(Qb, Kb, Pbuf, Zful);
  pv_kernel<<<512, 256, 0, stream>>>(Pbuf, Vtb, sufx, Zful, out);
}